// Round 10
// baseline (1037.769 us; speedup 1.0000x reference)
//
#include <hip/hip_runtime.h>
#include <hip/hip_bf16.h>
#include <cstdint>
#include <cstddef>

using bf16 = __hip_bfloat16;

typedef __attribute__((ext_vector_type(8))) short short8;     // bf16x8 MFMA A/B frag
typedef __attribute__((ext_vector_type(16))) float f32x16;    // 32x32 MFMA C/D frag
typedef __attribute__((ext_vector_type(4))) unsigned short us4;

static constexpr int Bb = 4, Ss = 2048, Hh = 2048, Ii = 8192, Gg = 128;
static constexpr int Mm = Bb * Ss;   // 8192 tokens

#define MEMFENCE() asm volatile("" ::: "memory")
#define BARRIER() do { MEMFENCE(); __builtin_amdgcn_s_barrier(); MEMFENCE(); } while (0)

// ---------------------------------------------------------------------------
// 1-bit group quantization: wq = sign(w) * mean(|w|) per contiguous 128-group.
// ---------------------------------------------------------------------------
__global__ void quant_onebit(const float* __restrict__ w, bf16* __restrict__ wq,
                             int ngroups) {
  int gid = blockIdx.x * 4 + (threadIdx.x >> 6);
  if (gid >= ngroups) return;
  int lane = threadIdx.x & 63;
  size_t base = (size_t)gid * Gg + (size_t)lane * 2;
  float2 v = *(const float2*)(w + base);
  float s = fabsf(v.x) + fabsf(v.y);
#pragma unroll
  for (int m = 32; m >= 1; m >>= 1) s += __shfl_xor(s, m);
  float scale = s * (1.0f / 128.0f);
  float q0 = (v.x > 0.f) ? scale : ((v.x < 0.f) ? -scale : 0.f);
  float q1 = (v.y > 0.f) ? scale : ((v.y < 0.f) ? -scale : 0.f);
  unsigned int p =
      (unsigned int)__builtin_bit_cast(unsigned short, __float2bfloat16(q0)) |
      ((unsigned int)__builtin_bit_cast(unsigned short, __float2bfloat16(q1)) << 16);
  *(unsigned int*)(wq + base) = p;
}

__global__ void cast_f32_bf16(const float* __restrict__ in, bf16* __restrict__ out,
                              size_t n4) {
  size_t i = (size_t)blockIdx.x * blockDim.x + threadIdx.x;
  if (i >= n4) return;
  float4 v = *(const float4*)(in + i * 4);
  us4 o;
  o.x = __builtin_bit_cast(unsigned short, __float2bfloat16(v.x));
  o.y = __builtin_bit_cast(unsigned short, __float2bfloat16(v.y));
  o.z = __builtin_bit_cast(unsigned short, __float2bfloat16(v.z));
  o.w = __builtin_bit_cast(unsigned short, __float2bfloat16(v.w));
  *(us4*)(out + i * 4) = o;
}

// ---------------------------------------------------------------------------
// 256-row GEMM, mfma_f32_32x32x16_bf16. K split into 16-col units, each unit
// = A[256][32B] (8K) + B[256][32B] (8K) in a 6-slot LDS ring (96 KiB).
// Swizzle: phys 16B-slot = s ^ ((row>>2)&1)  -> every 16-lane LDS phase of a
// 32-row b128 frag read hits 8 bank-starts x 2 lanes (free, m136); staging
// source inverse-swizzled, dest linear (rule #21).
// Group = 2 units: {vmcnt(4); barrier; [reads u0; stage u0+4; 8 MFMA];
// [reads u1; stage u0+5; 8 MFMA]}  -- 1 barrier / 32k, counted vmcnt,
// lag stage->use = 2 groups (~2000 cyc > HBM 900). setprio on MFMA clusters.
// Chunked-N XCD mapping (R6). DUAL: two 128-col B panels + silu -> bf16.
// ---------------------------------------------------------------------------
__device__ __forceinline__ void gload16(const bf16* g, char* l) {
  __builtin_amdgcn_global_load_lds(
      (const __attribute__((address_space(1))) void*)g,
      (__attribute__((address_space(3))) void*)l, 16, 0, 0);
}

template <bool DUAL>
__global__ __launch_bounds__(512, 1)
void gemm32(const bf16* __restrict__ A,   // [M,K]
            const bf16* __restrict__ B0,  // [N,K]
            const bf16* __restrict__ B1,  // [N,K] (DUAL)
            bf16* __restrict__ OutBf,     // [M,N] (DUAL)
            float* __restrict__ OutF,     // [M,N] (!DUAL)
            int M, int N, int K) {
  constexpr int BM = 256, BN = DUAL ? 128 : 256;
  extern __shared__ char smem[];          // 6 x 16384 = 98304 B

  const int tid = threadIdx.x;
  const int wid = tid >> 6;               // 0..7
  const int lane = tid & 63;
  const int wr = wid >> 2;                // 0..1 row half (128 rows)
  const int wc = wid & 3;                 // 0..3 col quarter
  const int l31 = lane & 31;
  const int lh = lane >> 5;               // k-half (8 elems) within 16-k unit

  // ---- locality mapping: XCD-bijective, then chunk N (CN=8 n-blocks x all
  // m-blocks per chunk). nbx % 8 == 0 (64 dual, 8 single).
  const int nbx = N / BN;
  const int nbm = M / BM;
  const int nwg = (int)gridDim.x;
  const int cpx = nwg >> 3;
  const int wg = (int)blockIdx.x;
  const int L = (wg & 7) * cpx + (wg >> 3);
  constexpr int CN = 8;
  const int chunk = L / (nbm * CN);
  const int within = L % (nbm * CN);
  const int m0 = (within / CN) * BM;
  const int n0 = (chunk * CN + (within % CN)) * BN;

  const int NU = K >> 4;                  // 16-k units: 128 / 512
  const int NG = NU >> 1;                 // groups of 2 units

  // ---- staging: thread covers (row = tid>>1, phys half = tid&1) of a
  // [256][32B] unit; dest linear; source k-half inverse-swizzled.
  const int srow = tid >> 1;              // 0..255
  const int scol = (((tid & 1) ^ ((tid >> 3) & 1)) << 3);
  const bf16* pA = A + (size_t)(m0 + srow) * K + scol;
  const bf16* pB;
  if constexpr (DUAL)
    pB = (srow < 128 ? B0 + (size_t)(n0 + srow) * K
                     : B1 + (size_t)(n0 + srow - 128) * K) + scol;
  else
    pB = B0 + (size_t)(n0 + srow) * K + scol;
  const int dA = wid * 1024;

  auto stage = [&](int v, int slot) {     // 2 loads: unit v -> ring slot
    char* b = smem + slot * 16384;
    gload16(pA + v * 16, b + dA);
    gload16(pB + v * 16, b + 8192 + dA);
  };

  // swizzled frag read: 32B rows, phys slot = lh ^ ((row>>2)&1)
  auto lf = [&](const char* part, int row) -> short8 {
    return *(const short8*)(part + row * 32 + (((lh ^ (row >> 2)) & 1) << 4));
  };

  const f32x16 vzero = {0.f};
  f32x16 acc0[4], acc1[4];
#pragma unroll
  for (int mf = 0; mf < 4; ++mf) { acc0[mf] = vzero; acc1[mf] = vzero; }

  // ---- prologue: stage units 0..3 into slots 0..3 (8 loads)
  stage(0, 0); stage(1, 1); stage(2, 2); stage(3, 3);

  short8 fa[4], fb0, fb1;
  int sb = 0;                             // ring slot of group's first unit

  for (int g = 0; g < NG; ++g) {
    // entry: retire this group's 2 units; keep next 2 in flight
    if (g + 1 < NG) asm volatile("s_waitcnt vmcnt(4)" ::: "memory");
    else            asm volatile("s_waitcnt vmcnt(0)" ::: "memory");
    BARRIER();

    const int u0 = 2 * g;
    const char* Au0 = smem + sb * 16384;
    const char* Au1 = Au0 + 16384;        // sb even, sb+1 <= 5
    int sp = sb + 4; if (sp >= 6) sp -= 6;

    // ==== unit u0: reads, stage u0+4, 8 MFMA
#pragma unroll
    for (int mf = 0; mf < 4; ++mf)
      fa[mf] = lf(Au0, wr * 128 + mf * 32 + l31);
    if constexpr (DUAL) {
      fb0 = lf(Au0 + 8192, wc * 32 + l31);
      fb1 = lf(Au0 + 8192, 128 + wc * 32 + l31);
    } else {
      fb0 = lf(Au0 + 8192, wc * 64 + l31);
      fb1 = lf(Au0 + 8192, wc * 64 + 32 + l31);
    }
    if (u0 + 4 < NU) stage(u0 + 4, sp);
    __builtin_amdgcn_s_setprio(1);
#pragma unroll
    for (int mf = 0; mf < 4; ++mf) {
      acc0[mf] = __builtin_amdgcn_mfma_f32_32x32x16_bf16(fa[mf], fb0, acc0[mf], 0, 0, 0);
      acc1[mf] = __builtin_amdgcn_mfma_f32_32x32x16_bf16(fa[mf], fb1, acc1[mf], 0, 0, 0);
    }
    __builtin_amdgcn_s_setprio(0);

    // ==== unit u1: reads, stage u0+5, 8 MFMA
#pragma unroll
    for (int mf = 0; mf < 4; ++mf)
      fa[mf] = lf(Au1, wr * 128 + mf * 32 + l31);
    if constexpr (DUAL) {
      fb0 = lf(Au1 + 8192, wc * 32 + l31);
      fb1 = lf(Au1 + 8192, 128 + wc * 32 + l31);
    } else {
      fb0 = lf(Au1 + 8192, wc * 64 + l31);
      fb1 = lf(Au1 + 8192, wc * 64 + 32 + l31);
    }
    if (u0 + 5 < NU) stage(u0 + 5, sp + 1);
    __builtin_amdgcn_s_setprio(1);
#pragma unroll
    for (int mf = 0; mf < 4; ++mf) {
      acc0[mf] = __builtin_amdgcn_mfma_f32_32x32x16_bf16(fa[mf], fb0, acc0[mf], 0, 0, 0);
      acc1[mf] = __builtin_amdgcn_mfma_f32_32x32x16_bf16(fa[mf], fb1, acc1[mf], 0, 0, 0);
    }
    __builtin_amdgcn_s_setprio(0);

    sb += 2; if (sb >= 6) sb = 0;
  }

  // ---- epilogue: 32x32 C/D col=lane&31, row=(r&3)+8*(r>>2)+4*(lane>>5)
  // (layout verified end-to-end in R4: absmax passed)
#pragma unroll
  for (int mf = 0; mf < 4; ++mf)
#pragma unroll
    for (int r = 0; r < 16; ++r) {
      const int row = m0 + wr * 128 + mf * 32 + (r & 3) + 8 * (r >> 2) + 4 * lh;
      if constexpr (DUAL) {
        const int col = n0 + wc * 32 + l31;
        float g = acc0[mf][r];
        float u = acc1[mf][r];
        OutBf[(size_t)row * N + col] =
            __float2bfloat16(g / (1.0f + expf(-g)) * u);
      } else {
        const int col = n0 + wc * 64 + l31;
        OutF[(size_t)row * N + col] = acc0[mf][r];
        OutF[(size_t)row * N + col + 32] = acc1[mf][r];
      }
    }
}

// ---------------------------------------------------------------------------
extern "C" void kernel_launch(void* const* d_in, const int* in_sizes, int n_in,
                              void* d_out, int out_size, void* d_ws, size_t ws_size,
                              hipStream_t stream) {
  const float* x = (const float*)d_in[0];
  const float* wg = (const float*)d_in[1];
  const float* wu = (const float*)d_in[2];
  const float* wd = (const float*)d_in[3];
  float* out = (float*)d_out;

  char* ws = (char*)d_ws;
  bf16* xq = (bf16*)(ws + 0);
  bf16* wgq = (bf16*)(ws + (size_t)33554432);
  bf16* wuq = (bf16*)(ws + (size_t)67108864);
  bf16* hbuf = (bf16*)(ws + (size_t)100663296);
  bf16* wdq = xq;  // xq dead after GEMM1

  auto* kDual = gemm32<true>;
  auto* kSingle = gemm32<false>;
  (void)hipFuncSetAttribute((const void*)kDual,
                            hipFuncAttributeMaxDynamicSharedMemorySize, 98304);
  (void)hipFuncSetAttribute((const void*)kSingle,
                            hipFuncAttributeMaxDynamicSharedMemorySize, 98304);

  const int ngW = (Ii * Hh) / Gg;
  quant_onebit<<<ngW / 4, 256, 0, stream>>>(wg, wgq, ngW);
  quant_onebit<<<ngW / 4, 256, 0, stream>>>(wu, wuq, ngW);

  const size_t n4 = (size_t)Mm * Hh / 4;
  cast_f32_bf16<<<(unsigned)((n4 + 255) / 256), 256, 0, stream>>>(x, xq, n4);

  // GEMM1 fused: h = silu(x@wgq^T) * (x@wuq^T)  [M=8192, N=8192, K=2048]
  kDual<<<(Mm / 256) * (Ii / 128), 512, 98304, stream>>>(
      xq, wgq, wuq, hbuf, nullptr, Mm, Ii, Hh);

  quant_onebit<<<ngW / 4, 256, 0, stream>>>(wd, wdq, ngW);

  // GEMM2: out = h @ wdq^T  [M=8192, N=2048, K=8192]
  kSingle<<<(Mm / 256) * (Hh / 256), 512, 98304, stream>>>(
      hbuf, wdq, nullptr, nullptr, out, Mm, Hh, Ii);
}

// Round 11
// 877.296 us; speedup vs baseline: 1.1829x; 1.1829x over previous
//
#include <hip/hip_runtime.h>
#include <hip/hip_bf16.h>
#include <cstdint>
#include <cstddef>

using bf16 = __hip_bfloat16;

typedef __attribute__((ext_vector_type(8))) short short8;     // bf16x8 MFMA A/B frag
typedef __attribute__((ext_vector_type(16))) float f32x16;    // 32x32 MFMA C/D frag
typedef __attribute__((ext_vector_type(4))) unsigned short us4;

static constexpr int Bb = 4, Ss = 2048, Hh = 2048, Ii = 8192, Gg = 128;
static constexpr int Mm = Bb * Ss;   // 8192 tokens

#define MEMFENCE() asm volatile("" ::: "memory")
#define BARRIER() do { MEMFENCE(); __builtin_amdgcn_s_barrier(); MEMFENCE(); } while (0)

// ---------------------------------------------------------------------------
// 1-bit group quantization: wq = sign(w) * mean(|w|) per contiguous 128-group.
// ---------------------------------------------------------------------------
__global__ void quant_onebit(const float* __restrict__ w, bf16* __restrict__ wq,
                             int ngroups) {
  int gid = blockIdx.x * 4 + (threadIdx.x >> 6);
  if (gid >= ngroups) return;
  int lane = threadIdx.x & 63;
  size_t base = (size_t)gid * Gg + (size_t)lane * 2;
  float2 v = *(const float2*)(w + base);
  float s = fabsf(v.x) + fabsf(v.y);
#pragma unroll
  for (int m = 32; m >= 1; m >>= 1) s += __shfl_xor(s, m);
  float scale = s * (1.0f / 128.0f);
  float q0 = (v.x > 0.f) ? scale : ((v.x < 0.f) ? -scale : 0.f);
  float q1 = (v.y > 0.f) ? scale : ((v.y < 0.f) ? -scale : 0.f);
  unsigned int p =
      (unsigned int)__builtin_bit_cast(unsigned short, __float2bfloat16(q0)) |
      ((unsigned int)__builtin_bit_cast(unsigned short, __float2bfloat16(q1)) << 16);
  *(unsigned int*)(wq + base) = p;
}

__global__ void cast_f32_bf16(const float* __restrict__ in, bf16* __restrict__ out,
                              size_t n4) {
  size_t i = (size_t)blockIdx.x * blockDim.x + threadIdx.x;
  if (i >= n4) return;
  float4 v = *(const float4*)(in + i * 4);
  us4 o;
  o.x = __builtin_bit_cast(unsigned short, __float2bfloat16(v.x));
  o.y = __builtin_bit_cast(unsigned short, __float2bfloat16(v.y));
  o.z = __builtin_bit_cast(unsigned short, __float2bfloat16(v.z));
  o.w = __builtin_bit_cast(unsigned short, __float2bfloat16(v.w));
  *(us4*)(out + i * 4) = o;
}

// ---------------------------------------------------------------------------
// 256-row GEMM, mfma_f32_32x32x16_bf16, on the R6 skeleton (same stage-call
// order, vmcnt(4) ledger, 4 barriers/tile, chunked-N XCD mapping, setprio).
// K tile=64 -> 2 slices of 32 -> each slice = 2 k-units of 16.
// Unit = A[256rows x 16k] (8K) + B[256 x 16k] (8K).
// LDS slot bijection F(row,kh) = (row>>5)*1024 + 64*(row&15)
//   + (((bit4(row)+2*kh) ^ ((row&15)>>1))&3)*16
// makes the frag-read address-of-lane function BYTE-IDENTICAL to the
// R3/R6 pattern that measured 0 bank conflicts across 5 rounds, while
// delivering lane -> (row=lane&31, kh=lane>>5) as the 32x32 MFMA requires.
// Staging source inverse-maps F (dest linear slot = 16*tid, verified
// algebraically); global_load_lds dest stays linear (rule #21).
// DUAL: B-half = panel0 rows 0-127 (gate), panel1 rows 128-255 (up);
// silu-combine epilogue -> bf16.  !DUAL: BN=256, f32 out.
// ---------------------------------------------------------------------------
__device__ __forceinline__ void gload16(const bf16* g, char* l) {
  __builtin_amdgcn_global_load_lds(
      (const __attribute__((address_space(1))) void*)g,
      (__attribute__((address_space(3))) void*)l, 16, 0, 0);
}

template <bool DUAL>
__global__ __launch_bounds__(512, 2)
void gemm32(const bf16* __restrict__ A,   // [M,K]
            const bf16* __restrict__ B0,  // [N,K]
            const bf16* __restrict__ B1,  // [N,K] (DUAL)
            bf16* __restrict__ OutBf,     // [M,N] (DUAL)
            float* __restrict__ OutF,     // [M,N] (!DUAL)
            int M, int N, int K) {
  constexpr int BM = 256, BN = DUAL ? 128 : 256;
  // LDS: buf[2] x slice[2] x (A_u0 8K, A_u1 8K, B_u0 8K, B_u1 8K) = 131072 B
  extern __shared__ char smem[];

  const int tid = threadIdx.x;
  const int wid = tid >> 6;               // 0..7
  const int lane = tid & 63;
  const int wr = wid >> 2;                // 0..1 row half (128 rows)
  const int wc = wid & 3;                 // 0..3 col quarter
  const int l31 = lane & 31;
  const int lrow = lane & 15;
  const int q = lane >> 4;                // 0..3
  const int lh = lane >> 5;               // kh for epilogue row formula
  // R3-identical read offset within a 1024B group:
  const int rdOff = 64 * lrow + (((q ^ (lrow >> 1)) & 3) << 4);

  // ---- locality mapping: XCD-bijective, then chunk N (CN=8 n-blocks x all
  // m-blocks per chunk). nbx % 8 == 0 (64 dual, 8 single).
  const int nbx = N / BN;
  const int nbm = M / BM;
  const int nwg = (int)gridDim.x;
  const int cpx = nwg >> 3;
  const int wg = (int)blockIdx.x;
  const int L = (wg & 7) * cpx + (wg >> 3);
  constexpr int CN = 8;
  const int chunk = L / (nbm * CN);
  const int within = L % (nbm * CN);
  const int m0 = (within / CN) * BM;
  const int n0 = (chunk * CN + (within % CN)) * BN;

  const int NT = K / 64;

  // ---- staging source (inverse of F; dest = unit_base + wid*1024 + lane*16):
  // thread covers slot u=tid: lrs=(u>>2)&15, c=u&3, q'=c^((lrs>>1)&3),
  // row = wid*32 + 16*(q'&1) + lrs, k-offset = 8*(q'>>1).
  const int lrs = (tid >> 2) & 15;
  const int cq = (tid & 3) ^ ((lrs >> 1) & 3);
  const int srow = (wid << 5) + ((cq & 1) << 4) + lrs;
  const int skoff = (cq >> 1) << 3;
  const bf16* pA = A + (size_t)(m0 + srow) * K + skoff;
  const bf16* pB;
  if constexpr (DUAL)
    pB = (srow < 128 ? B0 + (size_t)(n0 + srow) * K
                     : B1 + (size_t)(n0 + srow - 128) * K) + skoff;
  else
    pB = B0 + (size_t)(n0 + srow) * K + skoff;
  const int dA = wid * 1024;

  auto stageA = [&](int t, int p) {       // 2 loads: A units 0,1 of slice p
    char* b = smem + (size_t)(t & 1) * 65536 + p * 32768;
    const int koff = t * 64 + p * 32;
    gload16(pA + koff, b + dA);
    gload16(pA + koff + 16, b + 8192 + dA);
  };
  auto stageB = [&](int t, int p) {       // 2 loads: B units 0,1 of slice p
    char* b = smem + (size_t)(t & 1) * 65536 + p * 32768 + 16384;
    const int koff = t * 64 + p * 32;
    gload16(pB + koff, b + dA);
    gload16(pB + koff + 16, b + 8192 + dA);
  };

  // ---- frag group bases (x1024) -- fixed per thread
  const int gB0 = DUAL ? wc : (2 * wc);
  const int gB1 = DUAL ? (4 + wc) : (2 * wc + 1);

  const f32x16 vzero = {0.f};
  f32x16 acc0[4], acc1[4];
#pragma unroll
  for (int mf = 0; mf < 4; ++mf) { acc0[mf] = vzero; acc1[mf] = vzero; }

  // ---- prologue: stage tile0 (order sA0,sB0,sA1,sB1 = 8 loads)
  stageA(0, 0); stageB(0, 0);
  stageA(0, 1); stageB(0, 1);

  short8 fa[4], fb0, fb1;

  for (int t = 0; t < NT; ++t) {
    const char* buf = smem + (size_t)(t & 1) * 65536;
#pragma unroll
    for (int p = 0; p < 2; ++p) {
      const char* Sp = buf + p * 32768;

      // ===== phase (p,0): wait slice p; unit-0 reads; stage A(t+1,p); 8 MFMA
      if (p == 0 || t + 1 < NT)
        asm volatile("s_waitcnt vmcnt(4)" ::: "memory");
      else
        asm volatile("s_waitcnt vmcnt(0)" ::: "memory");
      BARRIER();
#pragma unroll
      for (int mf = 0; mf < 4; ++mf)
        fa[mf] = *(const short8*)(Sp + (wr * 4 + mf) * 1024 + rdOff);
      fb0 = *(const short8*)(Sp + 16384 + gB0 * 1024 + rdOff);
      fb1 = *(const short8*)(Sp + 16384 + gB1 * 1024 + rdOff);
      if (t + 1 < NT) stageA(t + 1, p);
      __builtin_amdgcn_s_setprio(1);
#pragma unroll
      for (int mf = 0; mf < 4; ++mf) {
        acc0[mf] = __builtin_amdgcn_mfma_f32_32x32x16_bf16(fa[mf], fb0, acc0[mf], 0, 0, 0);
        acc1[mf] = __builtin_amdgcn_mfma_f32_32x32x16_bf16(fa[mf], fb1, acc1[mf], 0, 0, 0);
      }
      __builtin_amdgcn_s_setprio(0);
      BARRIER();

      // ===== phase (p,1): unit-1 reads; stage B(t+1,p); 8 MFMA
#pragma unroll
      for (int mf = 0; mf < 4; ++mf)
        fa[mf] = *(const short8*)(Sp + 8192 + (wr * 4 + mf) * 1024 + rdOff);
      fb0 = *(const short8*)(Sp + 8192 + 16384 + gB0 * 1024 + rdOff);
      fb1 = *(const short8*)(Sp + 8192 + 16384 + gB1 * 1024 + rdOff);
      if (t + 1 < NT) stageB(t + 1, p);
      __builtin_amdgcn_s_setprio(1);
#pragma unroll
      for (int mf = 0; mf < 4; ++mf) {
        acc0[mf] = __builtin_amdgcn_mfma_f32_32x32x16_bf16(fa[mf], fb0, acc0[mf], 0, 0, 0);
        acc1[mf] = __builtin_amdgcn_mfma_f32_32x32x16_bf16(fa[mf], fb1, acc1[mf], 0, 0, 0);
      }
      __builtin_amdgcn_s_setprio(0);
    }
  }

  // ---- epilogue: 32x32 C/D col=lane&31, row=(r&3)+8*(r>>2)+4*(lane>>5)
  // (verified end-to-end R4/R7/R10: absmax passed)
#pragma unroll
  for (int mf = 0; mf < 4; ++mf)
#pragma unroll
    for (int r = 0; r < 16; ++r) {
      const int row = m0 + wr * 128 + mf * 32 + (r & 3) + 8 * (r >> 2) + 4 * lh;
      if constexpr (DUAL) {
        const int col = n0 + wc * 32 + l31;
        float g = acc0[mf][r];
        float u = acc1[mf][r];
        OutBf[(size_t)row * N + col] =
            __float2bfloat16(g / (1.0f + expf(-g)) * u);
      } else {
        const int col = n0 + wc * 64 + l31;
        OutF[(size_t)row * N + col] = acc0[mf][r];
        OutF[(size_t)row * N + col + 32] = acc1[mf][r];
      }
    }
}

// ---------------------------------------------------------------------------
extern "C" void kernel_launch(void* const* d_in, const int* in_sizes, int n_in,
                              void* d_out, int out_size, void* d_ws, size_t ws_size,
                              hipStream_t stream) {
  const float* x = (const float*)d_in[0];
  const float* wg = (const float*)d_in[1];
  const float* wu = (const float*)d_in[2];
  const float* wd = (const float*)d_in[3];
  float* out = (float*)d_out;

  char* ws = (char*)d_ws;
  bf16* xq = (bf16*)(ws + 0);
  bf16* wgq = (bf16*)(ws + (size_t)33554432);
  bf16* wuq = (bf16*)(ws + (size_t)67108864);
  bf16* hbuf = (bf16*)(ws + (size_t)100663296);
  bf16* wdq = xq;  // xq dead after GEMM1

  auto* kDual = gemm32<true>;
  auto* kSingle = gemm32<false>;
  (void)hipFuncSetAttribute((const void*)kDual,
                            hipFuncAttributeMaxDynamicSharedMemorySize, 131072);
  (void)hipFuncSetAttribute((const void*)kSingle,
                            hipFuncAttributeMaxDynamicSharedMemorySize, 131072);

  const int ngW = (Ii * Hh) / Gg;
  quant_onebit<<<ngW / 4, 256, 0, stream>>>(wg, wgq, ngW);
  quant_onebit<<<ngW / 4, 256, 0, stream>>>(wu, wuq, ngW);

  const size_t n4 = (size_t)Mm * Hh / 4;
  cast_f32_bf16<<<(unsigned)((n4 + 255) / 256), 256, 0, stream>>>(x, xq, n4);

  // GEMM1 fused: h = silu(x@wgq^T) * (x@wuq^T)  [M=8192, N=8192, K=2048]
  kDual<<<(Mm / 256) * (Ii / 128), 512, 131072, stream>>>(
      xq, wgq, wuq, hbuf, nullptr, Mm, Ii, Hh);

  quant_onebit<<<ngW / 4, 256, 0, stream>>>(wd, wdq, ngW);

  // GEMM2: out = h @ wdq^T  [M=8192, N=2048, K=8192]
  kSingle<<<(Mm / 256) * (Hh / 256), 512, 131072, stream>>>(
      hbuf, wdq, nullptr, nullptr, out, Mm, Hh, Ii);
}